// Round 5
// baseline (221.681 us; speedup 1.0000x reference)
//
#include <hip/hip_runtime.h>

#define SEQ   4096
#define CDIM  256
#define NHEAD 4
#define DHEAD 64
#define PSTRIDE 72   // P-buffer row stride (f16): 144 B rows -> 16B-aligned b128 reads
#define NSPLIT 8

typedef float    f32x4 __attribute__((ext_vector_type(4)));
typedef _Float16 f16x8 __attribute__((ext_vector_type(8)));
typedef _Float16 f16x4 __attribute__((ext_vector_type(4)));

__device__ __forceinline__ f16x8 cvt_frag(const float* __restrict__ p) {
    float4 f0 = *(const float4*)p;
    float4 f1 = *(const float4*)(p + 4);
    f16x8 r;
    r[0]=(_Float16)f0.x; r[1]=(_Float16)f0.y; r[2]=(_Float16)f0.z; r[3]=(_Float16)f0.w;
    r[4]=(_Float16)f1.x; r[5]=(_Float16)f1.y; r[6]=(_Float16)f1.z; r[7]=(_Float16)f1.w;
    return r;
}

// ---------------- Kernel 0: weight fp32->fp16 prep ----------------
__global__ __launch_bounds__(256) void sta_prep(
    const float* __restrict__ qw, const float* __restrict__ kw,
    const float* __restrict__ vw, const float* __restrict__ ow,
    _Float16* __restrict__ w16)
{
    const int mat = blockIdx.y;
    const float* src = (mat == 0) ? qw : (mat == 1) ? kw : (mat == 2) ? vw : ow;
    const int i = (blockIdx.x * 256 + threadIdx.x) * 8;
    *(f16x8*)(w16 + mat * 65536 + i) = cvt_frag(src + i);
}

// ---------------- Kernel 1: QKV projection ----------------
__global__ __launch_bounds__(256) void sta_qkv(
    const float* __restrict__ x, const _Float16* __restrict__ w16,
    const float* __restrict__ qb, const float* __restrict__ kb, const float* __restrict__ vb,
    _Float16* __restrict__ Qo, _Float16* __restrict__ Ko, _Float16* __restrict__ Vo)
{
    const int wave = threadIdx.x >> 6;
    const int lane = threadIdx.x & 63;
    const int l15  = lane & 15;
    const int quad = lane >> 4;
    const int mat  = blockIdx.y;
    const int half = blockIdx.z;
    const int row0 = blockIdx.x * 64 + wave * 16;

    const _Float16* w    = w16 + mat * 65536;
    const float*    bias = (mat == 0) ? qb : (mat == 1) ? kb : vb;

    f16x8 xf[8];
    const float* xrow = x + (row0 + l15) * CDIM + quad * 8;
    #pragma unroll
    for (int ks = 0; ks < 8; ks++) xf[ks] = cvt_frag(xrow + ks * 32);

    #pragma unroll 1
    for (int ct = 0; ct < 8; ct++) {
        const int ctg = half * 8 + ct;
        const _Float16* wr = w + (ctg * 16 + l15) * CDIM + quad * 8;
        f32x4 acc = {0.f, 0.f, 0.f, 0.f};
        if (mat < 2) {
            #pragma unroll
            for (int ks = 0; ks < 8; ks++)
                acc = __builtin_amdgcn_mfma_f32_16x16x32_f16(*(const f16x8*)(wr + ks * 32), xf[ks], acc, 0, 0, 0);
            const float4 bv = *(const float4*)(bias + ctg * 16 + quad * 4);
            const int c0 = ctg * 16 + quad * 4;
            const int h = c0 >> 6, d0 = c0 & 63;
            const int grow = row0 + l15, b = grow >> 12, n = grow & (SEQ - 1);
            const float sc = (mat == 0) ? 0.0625f : 1.0f;
            f16x4 o;
            o[0] = (_Float16)((acc[0] + bv.x) * sc);
            o[1] = (_Float16)((acc[1] + bv.y) * sc);
            o[2] = (_Float16)((acc[2] + bv.z) * sc);
            o[3] = (_Float16)((acc[3] + bv.w) * sc);
            _Float16* dst = ((mat == 0) ? Qo : Ko) + (((b * NHEAD + h) * SEQ + n) * DHEAD + d0);
            *(f16x4*)dst = o;
        } else {
            #pragma unroll
            for (int ks = 0; ks < 8; ks++)
                acc = __builtin_amdgcn_mfma_f32_16x16x32_f16(xf[ks], *(const f16x8*)(wr + ks * 32), acc, 0, 0, 0);
            const int c = ctg * 16 + l15;
            const int h = c >> 6, d = c & 63;
            const float bv = bias[c];
            const int grow0 = row0 + quad * 4, b = grow0 >> 12, n0 = grow0 & (SEQ - 1);
            f16x4 o;
            #pragma unroll
            for (int r = 0; r < 4; r++) o[r] = (_Float16)(acc[r] + bv);
            *(f16x4*)(Vo + (((b * NHEAD + h) * DHEAD + d) * SEQ + n0)) = o;
        }
    }
}

// ---------------- Kernel 2: flash attention, split-KV=8, swapped PV ----------------
// grid (64 q-tiles of 64, 8 bh, 8 kv-splits), 64 thr = 1 wave owning 64 Q-rows.
// QK^T swapped: S[kv][q]; PV swapped too: O'=MFMA(A=V, B=P) -> lane holds 4
// contiguous d per q => packed fp16 b64 partial stores, no transpose needed.
__global__ __launch_bounds__(64) void sta_attn(
    const _Float16* __restrict__ Q, const _Float16* __restrict__ K, const _Float16* __restrict__ Vt,
    const float* __restrict__ taup,
    _Float16* __restrict__ Opart, float* __restrict__ lfull)
{
    __shared__ __align__(16) _Float16 pbuf[64 * PSTRIDE];   // wave-private, no barriers

    const int lane = threadIdx.x;
    const int l15  = lane & 15;
    const int quad = lane >> 4;
    const int qt = blockIdx.x;   // 0..63
    const int bh = blockIdx.y;   // 0..7
    const int sp = blockIdx.z;   // 0..7
    const float tau_eff = fmaxf(taup[0], 0.0f);

    const _Float16* Qb = Q  + bh * SEQ * DHEAD;
    const _Float16* Kb = K  + bh * SEQ * DHEAD;
    const _Float16* Vb = Vt + bh * DHEAD * SEQ;

    const int q0 = qt * 64;

    // Q B-fragments held all sweep: col=l15 -> q, k=quad*8+j -> d
    f16x8 qf[4][2];
    #pragma unroll
    for (int qb = 0; qb < 4; qb++)
        #pragma unroll
        for (int ks = 0; ks < 2; ks++)
            qf[qb][ks] = *(const f16x8*)(Qb + (q0 + qb * 16 + l15) * DHEAD + ks * 32 + quad * 8);

    f32x4 O[4][4];   // [qb][db]: lane holds (d = db*16+quad*4+r, q = qb*16+l15)
    #pragma unroll
    for (int qb = 0; qb < 4; qb++)
        #pragma unroll
        for (int db = 0; db < 4; db++) O[qb][db] = (f32x4){0.f, 0.f, 0.f, 0.f};
    float rs[4] = {0.f, 0.f, 0.f, 0.f};   // per-lane denominator partials, q = q0+qb*16+l15

    #pragma unroll 1
    for (int kt = sp * 8; kt < sp * 8 + 8; kt++) {
        const int kv0 = kt * 64;

        // ---- S' = K Q^T: rows=kv, cols=q. Gate+exp, packed b64 P-writes.
        #pragma unroll
        for (int kb = 0; kb < 4; kb++) {
            const _Float16* kp = Kb + (kv0 + kb * 16 + l15) * DHEAD + quad * 8;
            f16x8 k0 = *(const f16x8*)kp;
            f16x8 k1 = *(const f16x8*)(kp + 32);
            #pragma unroll
            for (int qb = 0; qb < 4; qb++) {
                f32x4 a = {0.f, 0.f, 0.f, 0.f};
                a = __builtin_amdgcn_mfma_f32_16x16x32_f16(k0, qf[qb][0], a, 0, 0, 0);
                a = __builtin_amdgcn_mfma_f32_16x16x32_f16(k1, qf[qb][1], a, 0, 0, 0);
                f16x4 pk;
                float acc = 0.f;
                #pragma unroll
                for (int r = 0; r < 4; r++) {
                    float e = __expf(a[r]);
                    float p = (a[r] > tau_eff) ? e : 1.0f;   // gate-off -> exp(0)=1
                    acc += p;
                    pk[r] = (_Float16)p;
                }
                rs[qb] += acc;
                *(f16x4*)(pbuf + (qb * 16 + l15) * PSTRIDE + kb * 16 + quad * 4) = pk;
            }
        }

        // ---- O' += V P (A=V from global, B=P from LDS; same-wave, no barrier) ----
        #pragma unroll
        for (int ks = 0; ks < 2; ks++) {
            f16x8 pb[4];
            #pragma unroll
            for (int qb = 0; qb < 4; qb++)
                pb[qb] = *(const f16x8*)(pbuf + (qb * 16 + l15) * PSTRIDE + ks * 32 + quad * 8);
            #pragma unroll
            for (int db = 0; db < 4; db++) {
                f16x8 vf = *(const f16x8*)(Vb + (db * 16 + l15) * SEQ + kv0 + ks * 32 + quad * 8);
                #pragma unroll
                for (int qb = 0; qb < 4; qb++)
                    O[qb][db] = __builtin_amdgcn_mfma_f32_16x16x32_f16(vf, pb[qb], O[qb][db], 0, 0, 0);
            }
        }
    }

    // ---- epilogue: reduce denominators across quads, packed fp16 partial stores ----
    #pragma unroll
    for (int qb = 0; qb < 4; qb++) {
        float v = rs[qb];
        v += __shfl_xor(v, 16);
        v += __shfl_xor(v, 32);
        rs[qb] = v;
    }
    _Float16* Ob = Opart + (size_t)((sp * 8 + bh) * SEQ + q0) * DHEAD;
    #pragma unroll
    for (int qb = 0; qb < 4; qb++) {
        #pragma unroll
        for (int db = 0; db < 4; db++) {
            f16x4 ov;
            #pragma unroll
            for (int r = 0; r < 4; r++) ov[r] = (_Float16)O[qb][db][r];
            *(f16x4*)(Ob + (qb * 16 + l15) * DHEAD + db * 16 + quad * 4) = ov;
        }
    }
    if (quad == 0) {
        #pragma unroll
        for (int qb = 0; qb < 4; qb++)
            atomicAdd(&lfull[bh * SEQ + q0 + qb * 16 + l15], rs[qb]);
    }
}

// ---------------- Kernel 3: output projection (reads split partials directly) ----------------
// grid (256 row-tiles of 32, 4 channel-quarters), 128 thr = 2 waves of 16 rows.
__global__ __launch_bounds__(128) void sta_oproj(
    const _Float16* __restrict__ Opart, const float* __restrict__ lfull,
    const _Float16* __restrict__ w16o, const float* __restrict__ ob,
    float* __restrict__ out)
{
    const int wave = threadIdx.x >> 6;
    const int lane = threadIdx.x & 63;
    const int l15  = lane & 15;
    const int quad = lane >> 4;
    const int row0 = blockIdx.x * 32 + wave * 16;
    const int quarter = blockIdx.y;

    const int grow = row0 + l15;
    const int b = grow >> 12, n = grow & (SEQ - 1);

    // per-head inverse denominators for this token
    _Float16 inv[NHEAD];
    #pragma unroll
    for (int h = 0; h < NHEAD; h++)
        inv[h] = (_Float16)(1.0f / lfull[(b * NHEAD + h) * SEQ + n]);

    // A-fragments: ao[n][c] = (sum_sp Opart) * inv_l[head(c)]
    f16x8 af[8];
    #pragma unroll
    for (int ks = 0; ks < 8; ks++) {
        const int hq = ks * 4 + quad;            // 0..31
        const int h  = hq >> 3;
        const int d0 = (hq & 7) * 8;
        const _Float16* pp = Opart + (size_t)((b * NHEAD + h) * SEQ + n) * DHEAD + d0;
        f16x8 s = *(const f16x8*)pp;
        #pragma unroll
        for (int sp = 1; sp < NSPLIT; sp++)
            s = s + *(const f16x8*)(pp + (size_t)sp * 8 * SEQ * DHEAD);
        af[ks] = s * inv[h];
    }

    #pragma unroll 1
    for (int ct = 0; ct < 4; ct++) {
        const int ctg = quarter * 4 + ct;
        const _Float16* wr = w16o + (ctg * 16 + l15) * CDIM + quad * 8;
        f32x4 acc = {0.f, 0.f, 0.f, 0.f};
        #pragma unroll
        for (int ks = 0; ks < 8; ks++)
            acc = __builtin_amdgcn_mfma_f32_16x16x32_f16(*(const f16x8*)(wr + ks * 32), af[ks], acc, 0, 0, 0);
        const float4 bv = *(const float4*)(ob + ctg * 16 + quad * 4);
        const int c0 = ctg * 16 + quad * 4;
        float4 res;
        res.x = acc[0] + bv.x; res.y = acc[1] + bv.y;
        res.z = acc[2] + bv.z; res.w = acc[3] + bv.w;
        *(float4*)(out + (size_t)grow * CDIM + c0) = res;
    }
}

extern "C" void kernel_launch(void* const* d_in, const int* in_sizes, int n_in,
                              void* d_out, int out_size, void* d_ws, size_t ws_size,
                              hipStream_t stream) {
    const float* x   = (const float*)d_in[0];
    const float* qw  = (const float*)d_in[1];
    const float* qb  = (const float*)d_in[2];
    const float* kw  = (const float*)d_in[3];
    const float* kb  = (const float*)d_in[4];
    const float* vw  = (const float*)d_in[5];
    const float* vb  = (const float*)d_in[6];
    const float* ow  = (const float*)d_in[7];
    const float* ob  = (const float*)d_in[8];
    const float* tau = (const float*)d_in[9];

    // ws layout (f16 units unless noted):
    //   w16   : 262144            (512 KB)
    //   Q,K,Vt: 3 * 2097152       (12 MB)
    //   Opart : 8sp*8bh*4096*64 = 16777216   (32 MB fp16)
    //   lfull : 8bh*4096 fp32     (128 KB)
    _Float16* w16 = (_Float16*)d_ws;
    _Float16* Q   = w16 + 262144;
    _Float16* K   = Q + 2097152;
    _Float16* Vt  = K + 2097152;
    _Float16* Opart = Vt + 2097152;
    float* lfull  = (float*)(Opart + 16777216);

    sta_prep <<<dim3(32, 4),     256, 0, stream>>>(qw, kw, vw, ow, w16);
    sta_qkv  <<<dim3(128, 3, 2), 256, 0, stream>>>(x, w16, qb, kb, vb, Q, K, Vt);
    hipMemsetAsync(lfull, 0, NHEAD * 2 * SEQ * sizeof(float), stream);
    sta_attn <<<dim3(64, 8, 8),   64, 0, stream>>>(Q, K, Vt, tau, Opart, lfull);
    sta_oproj<<<dim3(256, 4),    128, 0, stream>>>(Opart, lfull, w16 + 3 * 65536, ob, (float*)d_out);
}